// Round 10
// baseline (4293.906 us; speedup 1.0000x reference)
//
#include <hip/hip_runtime.h>
#include <math.h>

#define N_TOK 1024
#define DV    400
#define G4    1600
#define DWD   300
#define DPD   100
#define HID   512
#define FD    128
#define GWG   50     // workgroups per LSTM direction (each dir on its own XCD)
#define EPW   8      // hidden elements per WG
#define NCHK  (DV/4) // 100 poll chunks of 4 slots

typedef unsigned uint32x4 __attribute__((ext_vector_type(4)));

__device__ __forceinline__ float sigmoidf_(float x){ return 1.0f/(1.0f+__expf(-x)); }
__device__ __forceinline__ float tanh_safe(float x){
    float t = __expf(-2.0f*fabsf(x));
    float r = (1.0f - t)/(1.0f + t);
    return copysignf(r, x);
}

#define LDA4(p) __hip_atomic_load((p), __ATOMIC_RELAXED, __HIP_MEMORY_SCOPE_AGENT)

// fast-path poll: sc0 load (bypass L1, hit XCD-local L2); "+&v" keeps zero-init live,
// waitcnt carries a register dependency so checks can't hoist (rule #18).
#define PLDF(X, P) asm volatile("global_load_dwordx4 %0, %1, off sc0" \
                                : "+&v"(X) : "v"(P) : "memory")
#define WT0(X)     asm volatile("s_waitcnt vmcnt(0)" : "+v"(X) :: "memory")

// ---------------- embedding gather ----------------
__global__ void k_gather(const int* __restrict__ wid, const int* __restrict__ pid,
                         const float* __restrict__ wemb, const float* __restrict__ pemb,
                         float* __restrict__ x)
{
    int t = blockIdx.x;
    int w = wid[t], p = pid[t];
    for (int k = threadIdx.x; k < DV; k += blockDim.x){
        float v = (k < DWD) ? wemb[(long)w*DWD + k] : pemb[p*DPD + (k - DWD)];
        x[t*DV + k] = v;
    }
}

// ---------------- tiny transpose (U_1 -> U_1^T) ----------------
__global__ void k_transpose(const float* __restrict__ U, float* __restrict__ Ut, int n)
{
    int j = blockIdx.y*16 + threadIdx.y;
    int k = blockIdx.x*16 + threadIdx.x;
    if (j < n && k < n) Ut[j*n + k] = U[k*n + j];
}

// ---------------- fp32 NT GEMM (single) ----------------
__global__ __launch_bounds__(256) void k_gemm_nt(
    const float* __restrict__ A, const float* __restrict__ B,
    const float* __restrict__ bias1, const float* __restrict__ rowbias,
    float* __restrict__ C, int M, int Nn, int K)
{
    const int BM = 64, BN = 64, BK = 16;
    __shared__ float As[BK][BM];
    __shared__ float Bs[BK][BN];
    int tid = threadIdx.x;
    int tx = tid & 15, ty = tid >> 4;
    int m0 = blockIdx.y*BM, n0 = blockIdx.x*BN;
    int lrow = tid >> 2, lk = (tid & 3) * 4;
    float acc[4][4] = {{0.f}};
    for (int k0 = 0; k0 < K; k0 += BK){
        const float4 av = *(const float4*)&A[(long)(m0+lrow)*K + k0 + lk];
        const float4 bv = *(const float4*)&B[(long)(n0+lrow)*K + k0 + lk];
        As[lk+0][lrow]=av.x; As[lk+1][lrow]=av.y; As[lk+2][lrow]=av.z; As[lk+3][lrow]=av.w;
        Bs[lk+0][lrow]=bv.x; Bs[lk+1][lrow]=bv.y; Bs[lk+2][lrow]=bv.z; Bs[lk+3][lrow]=bv.w;
        __syncthreads();
        #pragma unroll
        for (int kk = 0; kk < BK; ++kk){
            const float4 a = *(const float4*)&As[kk][ty*4];
            const float4 b = *(const float4*)&Bs[kk][tx*4];
            const float ar[4]={a.x,a.y,a.z,a.w}, br[4]={b.x,b.y,b.z,b.w};
            #pragma unroll
            for (int i=0;i<4;++i)
                #pragma unroll
                for (int j=0;j<4;++j) acc[i][j] += ar[i]*br[j];
        }
        __syncthreads();
    }
    #pragma unroll
    for (int i=0;i<4;++i){
        int m = m0 + ty*4 + i;
        float rb = rowbias ? rowbias[m] : 0.0f;
        #pragma unroll
        for (int j=0;j<4;++j){
            int n = n0 + tx*4 + j;
            float v = acc[i][j] + rb;
            if (bias1) v += bias1[n];
            C[(long)m*Nn + n] = v;
        }
    }
}

// ---------------- fp32 NT GEMM, z-merged pair ----------------
__global__ __launch_bounds__(256) void k_gemm_ntz(
    const float* __restrict__ A0, const float* __restrict__ A1,
    const float* __restrict__ B0, const float* __restrict__ B1,
    const float* __restrict__ c10, const float* __restrict__ c11,
    const float* __restrict__ c20, const float* __restrict__ c21,
    float* __restrict__ C0, float* __restrict__ C1,
    int M, int Nn, int K, int rev1, int relu)
{
    const float* A = blockIdx.z ? A1 : A0;
    const float* B = blockIdx.z ? B1 : B0;
    const float* bias1 = blockIdx.z ? c11 : c10;
    const float* bias2 = blockIdx.z ? c21 : c20;
    float* C = blockIdx.z ? C1 : C0;
    int revA = blockIdx.z ? rev1 : 0;

    const int BM = 64, BN = 64, BK = 16;
    __shared__ float As[BK][BM];
    __shared__ float Bs[BK][BN];
    int tid = threadIdx.x;
    int tx = tid & 15, ty = tid >> 4;
    int m0 = blockIdx.y*BM, n0 = blockIdx.x*BN;
    int lrow = tid >> 2, lk = (tid & 3) * 4;
    float acc[4][4] = {{0.f}};
    for (int k0 = 0; k0 < K; k0 += BK){
        int am = m0 + lrow; if (revA) am = M - 1 - am;
        const float4 av = *(const float4*)&A[(long)am*K + k0 + lk];
        const float4 bv = *(const float4*)&B[(long)(n0+lrow)*K + k0 + lk];
        As[lk+0][lrow]=av.x; As[lk+1][lrow]=av.y; As[lk+2][lrow]=av.z; As[lk+3][lrow]=av.w;
        Bs[lk+0][lrow]=bv.x; Bs[lk+1][lrow]=bv.y; Bs[lk+2][lrow]=bv.z; Bs[lk+3][lrow]=bv.w;
        __syncthreads();
        #pragma unroll
        for (int kk = 0; kk < BK; ++kk){
            const float4 a = *(const float4*)&As[kk][ty*4];
            const float4 b = *(const float4*)&Bs[kk][tx*4];
            const float ar[4]={a.x,a.y,a.z,a.w}, br[4]={b.x,b.y,b.z,b.w};
            #pragma unroll
            for (int i=0;i<4;++i)
                #pragma unroll
                for (int j=0;j<4;++j) acc[i][j] += ar[i]*br[j];
        }
        __syncthreads();
    }
    #pragma unroll
    for (int i=0;i<4;++i){
        int m = m0 + ty*4 + i;
        #pragma unroll
        for (int j=0;j<4;++j){
            int n = n0 + tx*4 + j;
            float v = acc[i][j];
            if (bias1) v += bias1[n];
            if (bias2) v += bias2[n];
            if (relu)  v = fmaxf(v, 0.0f);
            C[(long)m*Nn + n] = v;
        }
    }
}

// -------- persistent BiLSTM — per-XCD placement, L2 fast mailbox + agent shadow --------
// fwd dir runs on XCD0, bwd on XCD1 (dirs never communicate). Within an XCD, the 50 WGs
// (2/CU, LDS 54.5KB) exchange h through an XCD-LOCAL L2 mailbox: producer stores with
// sc0 (write-through past the write-back L1 — r7's missing piece), consumers poll with
// sc0 dwordx4 loads (bypass L1, hit shared L2, ~300cy RT). Every value is ALSO published
// to a separate agent-scope shadow mailbox (IF$, r3-proven): if the fast path fails, the
// poller falls back to shadow polling, and after 2 failed steps stops trying the fast
// path (bounded waste). Slot = bits(h)|1 (4B, memset-0 = empty; LSB err < 6e-8).
__global__ __launch_bounds__(256) void k_lstm(
    const float* __restrict__ Whh_f, const float* __restrict__ Whh_b,
    const float* __restrict__ Xf, const float* __restrict__ Xb,
    const float* __restrict__ h0, const float* __restrict__ c0,
    unsigned* __restrict__ fastm, unsigned* __restrict__ shadow,
    int* __restrict__ tickets)
{
    __shared__ float W_s[32][DV];                 // 51.2 KB
    __shared__ __align__(16) float hA[DV];
    __shared__ __align__(16) float hB[DV];
    __shared__ int rank_s;

    unsigned xcc;
    asm volatile("s_getreg_b32 %0, hwreg(HW_REG_XCC_ID)" : "=s"(xcc));
    if (xcc > 1) return;                  // dirs live on XCD0 (fwd) and XCD1 (bwd)

    int tid = threadIdx.x;
    int dir = (int)xcc;
    if (tid == 0) rank_s = atomicAdd(&tickets[dir], 1);
    __syncthreads();
    int g = rank_s;
    if (g >= GWG) return;                 // not selected; frees the CU slot

    int j0  = g * EPW;
    const float* Whh = dir ? Whh_b : Whh_f;
    const float* XX  = dir ? Xb    : Xf;
    unsigned* fm = fastm  + (size_t)dir * N_TOK * DV;
    unsigned* sh = shadow + (size_t)dir * N_TOK * DV;

    // stage weight slice (r3-proven layout): local row r = q*8+e -> row q*DV + j0 + e
    for (int idx = tid; idx < 32*DV; idx += 256){
        int rr = idx / DV, k = idx % DV;
        int grow_ = (rr >> 3) * DV + j0 + (rr & 7);
        W_s[rr][k] = Whh[(long)grow_*DV + k];
    }
    for (int idx = tid; idx < DV; idx += 256) hA[idx] = h0[dir*DV + idx];

    // dot roles: 8 lanes/row
    int w    = tid >> 6;
    int lane = tid & 63;
    int q    = lane >> 4;
    int eo   = (lane >> 3) & 1;
    int l    = lane & 7;
    int e    = 2*w + eo;
    int r    = q*8 + e;
    int grow = q*DV + j0 + e;
    bool owner = (q == 0) && (l == 0);
    float c_reg = owner ? c0[dir*DV + j0 + e] : 0.0f;

    // poll role: threads 0..99 own one 4-slot chunk; own-WG chunks skipped
    int  cid    = tid;
    bool isPoll = (tid < NCHK) && (cid != 2*g) && (cid != 2*g + 1);
    __syncthreads();

    float xv_n = (l == 0) ? XX[grow] : 0.0f;   // X prefetch for t=0

    bool dead = false, useFast = true;
    int  fastFails = 0;
    for (int t = 0; t < N_TOK; ++t){
        const float* hc = (t & 1) ? hB : hA;
        float*       hn = (t & 1) ? hA : hB;
        float xv = xv_n;

        // matvec: row r dot h (8 lanes/row, float2 each, W fp32 in LDS)
        const float2* wrow = (const float2*)&W_s[r][0];
        const float2* hp   = (const float2*)hc;
        float sum = 0.0f;
        #pragma unroll
        for (int i = 0; i < 25; ++i){
            float2 wv = wrow[l + 8*i];
            float2 hv = hp[l + 8*i];
            sum = fmaf(wv.x, hv.x, sum);
            sum = fmaf(wv.y, hv.y, sum);
        }
        sum += __shfl_xor(sum, 1, 8);
        sum += __shfl_xor(sum, 2, 8);
        sum += __shfl_xor(sum, 4, 8);
        if (l == 0) sum += xv;

        float gi = __shfl(sum, eo*8 + 0,  64);
        float gf = __shfl(sum, eo*8 + 16, 64);
        float gg = __shfl(sum, eo*8 + 32, 64);
        float go = __shfl(sum, eo*8 + 48, 64);

        if (owner){
            float iv = sigmoidf_(gi), fv = sigmoidf_(gf);
            float gv = tanh_safe(gg), ov = sigmoidf_(go);
            c_reg = fv*c_reg + iv*gv;
            float hvv = ov * tanh_safe(c_reg);
            unsigned pk = __float_as_uint(hvv) | 1u;
            unsigned* fs = fm + (size_t)t*DV + j0 + e;
            asm volatile("global_store_dword %0, %1, off sc0"   // write-through to L2
                         :: "v"(fs), "v"(pk) : "memory");
            __hip_atomic_store(sh + (size_t)t*DV + j0 + e, pk,   // shadow: IF$
                               __ATOMIC_RELAXED, __HIP_MEMORY_SCOPE_AGENT);
            hn[j0 + e] = hvv;
        }

        // X prefetch for t+1 (flight hides under the poll)
        if (l == 0){
            int tn = (t + 1 < N_TOK) ? (t + 1) : t;
            xv_n = XX[(size_t)tn*G4 + grow];
        }

        if (isPoll && !dead){
            const unsigned* pf = fm + (size_t)t*DV + 4*cid;
            const unsigned* ps = sh + (size_t)t*DV + 4*cid;
            bool got = false;
            if (useFast){
                uint32x4 A = {0,0,0,0};
                PLDF(A, pf);
                int it = 0;
                for (;;){
                    WT0(A);
                    if (A.x && A.y && A.z && A.w){ got = true; break; }
                    if (++it > 32) break;
                    PLDF(A, pf);
                }
                if (got){
                    float4 f;
                    f.x = __uint_as_float(A.x); f.y = __uint_as_float(A.y);
                    f.z = __uint_as_float(A.z); f.w = __uint_as_float(A.w);
                    *(float4*)&hn[4*cid] = f;
                } else {
                    if (++fastFails >= 2) useFast = false;   // bounded fast-path waste
                }
            }
            if (!got){
                // r3/r9-proven agent-scope fallback on the shadow mailbox
                bool d0=false,d1=false,d2=false,d3=false;
                int guard = 0;
                while (!(d0 && d1 && d2 && d3)){
                    if (!d0){ unsigned u = LDA4(ps+0); if (u){ hn[4*cid+0]=__uint_as_float(u); d0=true; } }
                    if (!d1){ unsigned u = LDA4(ps+1); if (u){ hn[4*cid+1]=__uint_as_float(u); d1=true; } }
                    if (!d2){ unsigned u = LDA4(ps+2); if (u){ hn[4*cid+2]=__uint_as_float(u); d2=true; } }
                    if (!d3){ unsigned u = LDA4(ps+3); if (u){ hn[4*cid+3]=__uint_as_float(u); d3=true; } }
                    if (++guard > (1 << 18)) { dead = true; break; }   // no-hang safety
                }
            }
        }
        __syncthreads();   // hn complete; hc free for next step's writers
    }
}

// ---------------- sr = sigmoid(concat(hF[t], hB[N-1-t])) from the shadow mailbox ------
__global__ void k_sr(const float* __restrict__ shadow, float* __restrict__ sr)
{
    int t = blockIdx.x;
    const float* mF = shadow;
    const float* mB = shadow + (size_t)N_TOK * DV;
    for (int c = threadIdx.x; c < 2*DV; c += blockDim.x){
        float v = (c < DV) ? mF[(size_t)t*DV + c]
                           : mB[(size_t)(N_TOK-1-t)*DV + (c - DV)];
        sr[t*2*DV + c] = 1.0f/(1.0f+__expf(-v));
    }
}

// ---------------- bvec[i] = dot(Hh[i], u2) ----------------
__global__ void k_bvec(const float* __restrict__ Hh, const float* __restrict__ u2,
                       float* __restrict__ bvec)
{
    int i = blockIdx.x;
    int lane = threadIdx.x;
    float v = Hh[i*FD + lane]*u2[lane] + Hh[i*FD + 64 + lane]*u2[64 + lane];
    v += __shfl_xor(v, 1, 64);
    v += __shfl_xor(v, 2, 64);
    v += __shfl_xor(v, 4, 64);
    v += __shfl_xor(v, 8, 64);
    v += __shfl_xor(v, 16, 64);
    v += __shfl_xor(v, 32, 64);
    if (lane == 0) bvec[i] = v;
}

extern "C" void kernel_launch(void* const* d_in, const int* in_sizes, int n_in,
                              void* d_out, int out_size, void* d_ws, size_t ws_size,
                              hipStream_t stream)
{
    const int*   word_ids = (const int*)  d_in[0];
    const int*   pos_ids  = (const int*)  d_in[1];
    const float* h0    = (const float*)d_in[2];
    const float* c0    = (const float*)d_in[3];
    const float* wemb  = (const float*)d_in[4];
    const float* pemb  = (const float*)d_in[5];
    const float* Wih_f = (const float*)d_in[6];
    const float* Whh_f = (const float*)d_in[7];
    const float* bih_f = (const float*)d_in[8];
    const float* bhh_f = (const float*)d_in[9];
    const float* Wih_b = (const float*)d_in[10];
    const float* Whh_b = (const float*)d_in[11];
    const float* bih_b = (const float*)d_in[12];
    const float* bhh_b = (const float*)d_in[13];
    const float* Wh1   = (const float*)d_in[14];
    const float* bh1   = (const float*)d_in[15];
    const float* Wh2   = (const float*)d_in[16];
    const float* bh2   = (const float*)d_in[17];
    const float* Wd1   = (const float*)d_in[18];
    const float* bd1   = (const float*)d_in[19];
    const float* Wd2   = (const float*)d_in[20];
    const float* bd2   = (const float*)d_in[21];
    const float* U1    = (const float*)d_in[22];
    const float* u2    = (const float*)d_in[23];
    float* out = (float*)d_out;

    // workspace layout (floats)
    float* ws  = (float*)d_ws;
    float* x    = ws;                               // [0, 409600)
    float* Xf   = ws + 409600;                      // [409600, 2048000)
    float* Xb   = ws + 2048000;                     // [2048000, 3686400)
    unsigned* fastm  = (unsigned*)(ws + 3686400);   // [3686400, 4505600)
    unsigned* shadow = (unsigned*)(ws + 4505600);   // [4505600, 5324800)
    float* sr   = ws + 5324800;                     // [5324800, 6144000)
    float* T1h  = ws + 6144000;                     // [6144000, 6668288)
    float* T1d  = ws + 6668288;                     // [6668288, 7192576)
    float* Hh   = ws + 7192576;                     // [7192576, 7323648)
    float* Hd   = ws + 7323648;                     // [7323648, 7454720)
    float* G1   = ws + 7454720;                     // [7454720, 7585792)
    float* Ut   = ws + 7585792;                     // [7585792, 7602176)
    float* bvec = ws + 7602176;                     // [7602176, 7603200)
    int*   tickets = (int*)(ws + 7603200);          // 2 ints

    // zero both mailboxes (contiguous) + tickets
    hipMemsetAsync(fastm, 0, (size_t)2 * 2*N_TOK*DV*sizeof(unsigned), stream);
    hipMemsetAsync(tickets, 0, 2*sizeof(int), stream);

    k_gather<<<N_TOK, 128, 0, stream>>>(word_ids, pos_ids, wemb, pemb, x);
    k_transpose<<<dim3(8,8), dim3(16,16), 0, stream>>>(U1, Ut, FD);

    dim3 blk(256);
    // input projections, z-merged: Xf = x@Wih_f^T + b..; Xb = rev(x)@Wih_b^T + b..
    k_gemm_ntz<<<dim3(G4/64, N_TOK/64, 2), blk, 0, stream>>>(
        x, x, Wih_f, Wih_b, bih_f, bih_b, bhh_f, bhh_b, Xf, Xb,
        N_TOK, G4, DV, 1, 0);

    // sequential recurrence: oversubscribed; fwd WGs self-select on XCD0, bwd on XCD1
    k_lstm<<<2048, 256, 0, stream>>>(Whh_f, Whh_b, Xf, Xb, h0, c0,
                                     fastm, shadow, tickets);

    k_sr<<<N_TOK, 256, 0, stream>>>((const float*)shadow, sr);

    // MLP layer 1 (z-merged, relu) and layer 2 (z-merged)
    k_gemm_ntz<<<dim3(HID/64, N_TOK/64, 2), blk, 0, stream>>>(
        sr, sr, Wh1, Wd1, bh1, bd1, nullptr, nullptr, T1h, T1d,
        N_TOK, HID, 2*DV, 0, 1);
    k_gemm_ntz<<<dim3(FD/64, N_TOK/64, 2), blk, 0, stream>>>(
        T1h, T1d, Wh2, Wd2, bh2, bd2, nullptr, nullptr, Hh, Hd,
        N_TOK, FD, HID, 0, 0);
    // biaffine
    k_bvec<<<N_TOK, 64, 0, stream>>>(Hh, u2, bvec);
    k_gemm_nt<<<dim3(FD/64,  N_TOK/64), blk, 0, stream>>>(Hh, Ut, nullptr, nullptr, G1,
                                                          N_TOK, FD, FD);
    k_gemm_nt<<<dim3(N_TOK/64, N_TOK/64), blk, 0, stream>>>(G1, Hd, nullptr, bvec, out,
                                                            N_TOK, N_TOK, FD);
}

// Round 11
// 3193.036 us; speedup vs baseline: 1.3448x; 1.3448x over previous
//
#include <hip/hip_runtime.h>
#include <math.h>

#define N_TOK 1024
#define DV    400
#define G4    1600
#define DWD   300
#define DPD   100
#define HID   512
#define FD    128
#define GWG   50     // workgroups per LSTM direction (100 total)
#define EPW   8      // hidden elements per WG
#define PAD   4      // uints per mailbox slot (16B) — spreads poll traffic across lines

__device__ __forceinline__ float sigmoidf_(float x){ return 1.0f/(1.0f+__expf(-x)); }
__device__ __forceinline__ float tanh_safe(float x){
    float t = __expf(-2.0f*fabsf(x));
    float r = (1.0f - t)/(1.0f + t);
    return copysignf(r, x);
}

#define LDA(p) __hip_atomic_load((p), __ATOMIC_RELAXED, __HIP_MEMORY_SCOPE_AGENT)

// ---------------- embedding gather ----------------
__global__ void k_gather(const int* __restrict__ wid, const int* __restrict__ pid,
                         const float* __restrict__ wemb, const float* __restrict__ pemb,
                         float* __restrict__ x)
{
    int t = blockIdx.x;
    int w = wid[t], p = pid[t];
    for (int k = threadIdx.x; k < DV; k += blockDim.x){
        float v = (k < DWD) ? wemb[(long)w*DWD + k] : pemb[p*DPD + (k - DWD)];
        x[t*DV + k] = v;
    }
}

// ---------------- tiny transpose (U_1 -> U_1^T) ----------------
__global__ void k_transpose(const float* __restrict__ U, float* __restrict__ Ut, int n)
{
    int j = blockIdx.y*16 + threadIdx.y;
    int k = blockIdx.x*16 + threadIdx.x;
    if (j < n && k < n) Ut[j*n + k] = U[k*n + j];
}

// ---------------- fp32 NT GEMM (single) ----------------
__global__ __launch_bounds__(256) void k_gemm_nt(
    const float* __restrict__ A, const float* __restrict__ B,
    const float* __restrict__ bias1, const float* __restrict__ rowbias,
    float* __restrict__ C, int M, int Nn, int K)
{
    const int BM = 64, BN = 64, BK = 16;
    __shared__ float As[BK][BM];
    __shared__ float Bs[BK][BN];
    int tid = threadIdx.x;
    int tx = tid & 15, ty = tid >> 4;
    int m0 = blockIdx.y*BM, n0 = blockIdx.x*BN;
    int lrow = tid >> 2, lk = (tid & 3) * 4;
    float acc[4][4] = {{0.f}};
    for (int k0 = 0; k0 < K; k0 += BK){
        const float4 av = *(const float4*)&A[(long)(m0+lrow)*K + k0 + lk];
        const float4 bv = *(const float4*)&B[(long)(n0+lrow)*K + k0 + lk];
        As[lk+0][lrow]=av.x; As[lk+1][lrow]=av.y; As[lk+2][lrow]=av.z; As[lk+3][lrow]=av.w;
        Bs[lk+0][lrow]=bv.x; Bs[lk+1][lrow]=bv.y; Bs[lk+2][lrow]=bv.z; Bs[lk+3][lrow]=bv.w;
        __syncthreads();
        #pragma unroll
        for (int kk = 0; kk < BK; ++kk){
            const float4 a = *(const float4*)&As[kk][ty*4];
            const float4 b = *(const float4*)&Bs[kk][tx*4];
            const float ar[4]={a.x,a.y,a.z,a.w}, br[4]={b.x,b.y,b.z,b.w};
            #pragma unroll
            for (int i=0;i<4;++i)
                #pragma unroll
                for (int j=0;j<4;++j) acc[i][j] += ar[i]*br[j];
        }
        __syncthreads();
    }
    #pragma unroll
    for (int i=0;i<4;++i){
        int m = m0 + ty*4 + i;
        float rb = rowbias ? rowbias[m] : 0.0f;
        #pragma unroll
        for (int j=0;j<4;++j){
            int n = n0 + tx*4 + j;
            float v = acc[i][j] + rb;
            if (bias1) v += bias1[n];
            C[(long)m*Nn + n] = v;
        }
    }
}

// ---------------- fp32 NT GEMM, z-merged pair ----------------
__global__ __launch_bounds__(256) void k_gemm_ntz(
    const float* __restrict__ A0, const float* __restrict__ A1,
    const float* __restrict__ B0, const float* __restrict__ B1,
    const float* __restrict__ c10, const float* __restrict__ c11,
    const float* __restrict__ c20, const float* __restrict__ c21,
    float* __restrict__ C0, float* __restrict__ C1,
    int M, int Nn, int K, int rev1, int relu)
{
    const float* A = blockIdx.z ? A1 : A0;
    const float* B = blockIdx.z ? B1 : B0;
    const float* bias1 = blockIdx.z ? c11 : c10;
    const float* bias2 = blockIdx.z ? c21 : c20;
    float* C = blockIdx.z ? C1 : C0;
    int revA = blockIdx.z ? rev1 : 0;

    const int BM = 64, BN = 64, BK = 16;
    __shared__ float As[BK][BM];
    __shared__ float Bs[BK][BN];
    int tid = threadIdx.x;
    int tx = tid & 15, ty = tid >> 4;
    int m0 = blockIdx.y*BM, n0 = blockIdx.x*BN;
    int lrow = tid >> 2, lk = (tid & 3) * 4;
    float acc[4][4] = {{0.f}};
    for (int k0 = 0; k0 < K; k0 += BK){
        int am = m0 + lrow; if (revA) am = M - 1 - am;
        const float4 av = *(const float4*)&A[(long)am*K + k0 + lk];
        const float4 bv = *(const float4*)&B[(long)(n0+lrow)*K + k0 + lk];
        As[lk+0][lrow]=av.x; As[lk+1][lrow]=av.y; As[lk+2][lrow]=av.z; As[lk+3][lrow]=av.w;
        Bs[lk+0][lrow]=bv.x; Bs[lk+1][lrow]=bv.y; Bs[lk+2][lrow]=bv.z; Bs[lk+3][lrow]=bv.w;
        __syncthreads();
        #pragma unroll
        for (int kk = 0; kk < BK; ++kk){
            const float4 a = *(const float4*)&As[kk][ty*4];
            const float4 b = *(const float4*)&Bs[kk][tx*4];
            const float ar[4]={a.x,a.y,a.z,a.w}, br[4]={b.x,b.y,b.z,b.w};
            #pragma unroll
            for (int i=0;i<4;++i)
                #pragma unroll
                for (int j=0;j<4;++j) acc[i][j] += ar[i]*br[j];
        }
        __syncthreads();
    }
    #pragma unroll
    for (int i=0;i<4;++i){
        int m = m0 + ty*4 + i;
        #pragma unroll
        for (int j=0;j<4;++j){
            int n = n0 + tx*4 + j;
            float v = acc[i][j];
            if (bias1) v += bias1[n];
            if (bias2) v += bias2[n];
            if (relu)  v = fmaxf(v, 0.0f);
            C[(long)m*Nn + n] = v;
        }
    }
}

// ---------------- persistent BiLSTM — r3 structure + 16B-padded mailbox slots ---------
// Exact r3 exchange (relaxed agent-scope mailbox, depth-3 primed poll rings — proven
// 2.37us/step), with each 4B slot padded to its own 16B: a step's 400 slots spread over
// ~100 cache lines instead of 50, and pollers of adjacent slots no longer share lines.
// Theory: r3's wait is same-line serialization at the coherence point (~180 samples/line
// /step), not the IF$ hop itself. Slot = bits(h)|1 (memset-0 = empty; LSB err < 6e-8).
__global__ __launch_bounds__(256) void k_lstm(
    const float* __restrict__ Whh_f, const float* __restrict__ Whh_b,
    const float* __restrict__ Xf, const float* __restrict__ Xb,
    const float* __restrict__ h0, const float* __restrict__ c0,
    unsigned* __restrict__ mbox)
{
    __shared__ float W_s[32][DV];                 // 51.2 KB
    __shared__ __align__(16) float hA[DV];
    __shared__ __align__(16) float hB[DV];

    int tid = threadIdx.x;
    int dir = blockIdx.x / GWG;
    int g   = blockIdx.x % GWG;
    int j0  = g * EPW;
    const float* Whh = dir ? Whh_b : Whh_f;
    const float* XX  = dir ? Xb    : Xf;
    unsigned* mb = mbox + (size_t)dir * N_TOK * DV * PAD;

    // stage weight slice: local row r = q*8+e -> global gate row q*DV + j0 + e
    for (int idx = tid; idx < 32*DV; idx += 256){
        int rr = idx / DV, k = idx % DV;
        int grow_ = (rr >> 3) * DV + j0 + (rr & 7);
        W_s[rr][k] = Whh[(long)grow_*DV + k];
    }
    for (int idx = tid; idx < DV; idx += 256) hA[idx] = h0[dir*DV + idx];

    // dot roles (r3-proven): 8 lanes/row
    int w    = tid >> 6;        // wave 0..3
    int lane = tid & 63;
    int q    = lane >> 4;       // gate 0..3 (i,f,g,o)
    int eo   = (lane >> 3) & 1;
    int l    = lane & 7;        // lane within row octet
    int e    = 2*w + eo;        // element 0..7
    int r    = q*8 + e;         // local weight row
    int grow = q*DV + j0 + e;   // global gate row
    bool owner = (q == 0) && (l == 0);
    float c_reg = owner ? c0[dir*DV + j0 + e] : 0.0f;

    // poll roles: thread polls slot tid (and 256+tid if tid<144)
    int s0 = tid, s1 = 256 + tid;
    bool own0  = (s0 >= j0) && (s0 < j0 + EPW);
    bool skip1 = (tid >= DV - 256) || ((s1 >= j0) && (s1 < j0 + EPW));
    __syncthreads();

    float xv_n = (l == 0) ? XX[grow] : 0.0f;   // X prefetch for t=0

    bool dead = false;
    for (int t = 0; t < N_TOK; ++t){
        const float* hc = (t & 1) ? hB : hA;
        float*       hn = (t & 1) ? hA : hB;

        unsigned* rowb = mb + (size_t)t*DV*PAD;
        const unsigned* p0 = rowb + (size_t)s0*PAD;
        const unsigned* p1 = rowb + (size_t)((tid < DV-256) ? s1 : s0)*PAD;

        // prime the poll rings BEFORE computing (flight overlaps the dot)
        unsigned q0a = LDA(p0), q1a = LDA(p1);
        unsigned q0b = LDA(p0), q1b = LDA(p1);
        unsigned q0c = LDA(p0), q1c = LDA(p1);

        float xv = xv_n;
        // X prefetch for t+1 (lands during this step's poll)
        if (l == 0){
            int tn = (t + 1 < N_TOK) ? (t + 1) : t;
            xv_n = XX[(size_t)tn*G4 + grow];
        }

        // matvec: row r dot h (8 lanes/row, float2 each, W fp32 in LDS)
        const float2* wrow = (const float2*)&W_s[r][0];
        const float2* hp   = (const float2*)hc;
        float sum = 0.0f;
        #pragma unroll
        for (int i = 0; i < 25; ++i){
            float2 wv = wrow[l + 8*i];
            float2 hv = hp[l + 8*i];
            sum = fmaf(wv.x, hv.x, sum);
            sum = fmaf(wv.y, hv.y, sum);
        }
        sum += __shfl_xor(sum, 1, 8);
        sum += __shfl_xor(sum, 2, 8);
        sum += __shfl_xor(sum, 4, 8);
        if (l == 0) sum += xv;

        // gather the 4 gate totals for my wave's element e
        float gi = __shfl(sum, eo*8 + 0,  64);
        float gf = __shfl(sum, eo*8 + 16, 64);
        float gg = __shfl(sum, eo*8 + 32, 64);
        float go = __shfl(sum, eo*8 + 48, 64);

        if (owner){
            float iv = sigmoidf_(gi), fv = sigmoidf_(gf);
            float gv = tanh_safe(gg), ov = sigmoidf_(go);
            c_reg = fv*c_reg + iv*gv;
            float hvv = ov * tanh_safe(c_reg);
            unsigned pk = __float_as_uint(hvv) | 1u;   // LSB=1 marks "arrived"
            __hip_atomic_store(rowb + (size_t)(j0 + e)*PAD, pk,
                               __ATOMIC_RELAXED, __HIP_MEMORY_SCOPE_AGENT);
            hn[j0 + e] = hvv;                          // own elements bypass mailbox
        }

        // depth-3 pipelined poll (named regs; oldest-first check, reissue on miss)
        if (!dead){
            bool g0 = own0, g1 = skip1;
            int guard = 0;
            while (!(g0 && g1)){
                if (!g0){
                    if (q0a){ hn[s0] = __uint_as_float(q0a); g0 = true; }
                    else { q0a = q0b; q0b = q0c; q0c = LDA(p0); }
                }
                if (!g1){
                    if (q1a){ hn[s1] = __uint_as_float(q1a); g1 = true; }
                    else { q1a = q1b; q1b = q1c; q1c = LDA(p1); }
                }
                if (++guard > (1 << 18)) { dead = true; break; }  // no-hang safety
            }
        }
        __syncthreads();   // hn complete; hc free for next step's writers
    }
}

// ---------------- sr = sigmoid(concat(hF[t], hB[N-1-t])) from the padded mailbox ------
__global__ void k_sr(const unsigned* __restrict__ mbox, float* __restrict__ sr)
{
    int t = blockIdx.x;
    const unsigned* mF = mbox;
    const unsigned* mB = mbox + (size_t)N_TOK * DV * PAD;
    for (int c = threadIdx.x; c < 2*DV; c += blockDim.x){
        unsigned u = (c < DV)
            ? LDA(mF + ((size_t)t*DV + c)*PAD)
            : LDA(mB + ((size_t)(N_TOK-1-t)*DV + (c - DV))*PAD);
        float v = __uint_as_float(u);
        sr[t*2*DV + c] = 1.0f/(1.0f+__expf(-v));
    }
}

// ---------------- bvec[i] = dot(Hh[i], u2) ----------------
__global__ void k_bvec(const float* __restrict__ Hh, const float* __restrict__ u2,
                       float* __restrict__ bvec)
{
    int i = blockIdx.x;
    int lane = threadIdx.x;
    float v = Hh[i*FD + lane]*u2[lane] + Hh[i*FD + 64 + lane]*u2[64 + lane];
    v += __shfl_xor(v, 1, 64);
    v += __shfl_xor(v, 2, 64);
    v += __shfl_xor(v, 4, 64);
    v += __shfl_xor(v, 8, 64);
    v += __shfl_xor(v, 16, 64);
    v += __shfl_xor(v, 32, 64);
    if (lane == 0) bvec[i] = v;
}

extern "C" void kernel_launch(void* const* d_in, const int* in_sizes, int n_in,
                              void* d_out, int out_size, void* d_ws, size_t ws_size,
                              hipStream_t stream)
{
    const int*   word_ids = (const int*)  d_in[0];
    const int*   pos_ids  = (const int*)  d_in[1];
    const float* h0    = (const float*)d_in[2];
    const float* c0    = (const float*)d_in[3];
    const float* wemb  = (const float*)d_in[4];
    const float* pemb  = (const float*)d_in[5];
    const float* Wih_f = (const float*)d_in[6];
    const float* Whh_f = (const float*)d_in[7];
    const float* bih_f = (const float*)d_in[8];
    const float* bhh_f = (const float*)d_in[9];
    const float* Wih_b = (const float*)d_in[10];
    const float* Whh_b = (const float*)d_in[11];
    const float* bih_b = (const float*)d_in[12];
    const float* bhh_b = (const float*)d_in[13];
    const float* Wh1   = (const float*)d_in[14];
    const float* bh1   = (const float*)d_in[15];
    const float* Wh2   = (const float*)d_in[16];
    const float* bh2   = (const float*)d_in[17];
    const float* Wd1   = (const float*)d_in[18];
    const float* bd1   = (const float*)d_in[19];
    const float* Wd2   = (const float*)d_in[20];
    const float* bd2   = (const float*)d_in[21];
    const float* U1    = (const float*)d_in[22];
    const float* u2    = (const float*)d_in[23];
    float* out = (float*)d_out;

    // workspace layout (floats). Mailbox = 2*1024*400 slots x 16B = 13.1 MB.
    // Post-LSTM buffers alias the DEAD x/Xf/Xb regions (all unused after k_lstm).
    float* ws  = (float*)d_ws;
    float* x    = ws;                               // [0, 409600)        dead after proj
    float* Xf   = ws + 409600;                      // [409600, 2048000)  dead after lstm
    float* Xb   = ws + 2048000;                     // [2048000,3686400)  dead after lstm
    unsigned* mbox = (unsigned*)(ws + 3686400);     // [3686400, 6963200) 16B-padded slots
    float* Ut   = ws + 6963200;                     // [6963200, 6979584)
    float* bvec = ws + 6979584;                     // [6979584, 6980608)
    // aliased over dead Xf/Xb after k_lstm:
    float* sr   = ws + 409600;                      // [409600, 1228800)
    float* T1h  = ws + 1228800;                     // [1228800, 1753088)
    float* T1d  = ws + 1753088;                     // [1753088, 2277376)
    float* Hh   = ws + 2277376;                     // [2277376, 2408448)
    float* Hd   = ws + 2408448;                     // [2408448, 2539520)
    float* G1   = ws + 2539520;                     // [2539520, 2670592)

    hipMemsetAsync(mbox, 0, (size_t)2*N_TOK*DV*PAD*sizeof(unsigned), stream);

    k_gather<<<N_TOK, 128, 0, stream>>>(word_ids, pos_ids, wemb, pemb, x);
    k_transpose<<<dim3(8,8), dim3(16,16), 0, stream>>>(U1, Ut, FD);

    dim3 blk(256);
    // input projections, z-merged: Xf = x@Wih_f^T + b..; Xb = rev(x)@Wih_b^T + b..
    k_gemm_ntz<<<dim3(G4/64, N_TOK/64, 2), blk, 0, stream>>>(
        x, x, Wih_f, Wih_b, bih_f, bih_b, bhh_f, bhh_b, Xf, Xb,
        N_TOK, G4, DV, 1, 0);

    // sequential recurrence: 100 WGs (50/dir), r3-proven structure + padded mailbox
    k_lstm<<<2*GWG, 256, 0, stream>>>(Whh_f, Whh_b, Xf, Xb, h0, c0, mbox);

    k_sr<<<N_TOK, 256, 0, stream>>>(mbox, sr);

    // MLP layer 1 (z-merged, relu) and layer 2 (z-merged)
    k_gemm_ntz<<<dim3(HID/64, N_TOK/64, 2), blk, 0, stream>>>(
        sr, sr, Wh1, Wd1, bh1, bd1, nullptr, nullptr, T1h, T1d,
        N_TOK, HID, 2*DV, 0, 1);
    k_gemm_ntz<<<dim3(FD/64, N_TOK/64, 2), blk, 0, stream>>>(
        T1h, T1d, Wh2, Wd2, bh2, bd2, nullptr, nullptr, Hh, Hd,
        N_TOK, FD, HID, 0, 0);
    // biaffine
    k_bvec<<<N_TOK, 64, 0, stream>>>(Hh, u2, bvec);
    k_gemm_nt<<<dim3(FD/64,  N_TOK/64), blk, 0, stream>>>(Hh, Ut, nullptr, nullptr, G1,
                                                          N_TOK, FD, FD);
    k_gemm_nt<<<dim3(N_TOK/64, N_TOK/64), blk, 0, stream>>>(G1, Hd, nullptr, bvec, out,
                                                            N_TOK, N_TOK, FD);
}